// Round 11
// baseline (257.995 us; speedup 1.0000x reference)
//
#include <hip/hip_runtime.h>
#include <hip/hip_bf16.h>
#include <cstddef>
#include <cstdint>

#define HID 1024
#define NHEADS 16
#define HDIM 64
#define BATCH 2
#define SEQ 2048
#define MROWS (BATCH * SEQ)   // 4096
#define BHT (BATCH * NHEADS)  // 32

typedef __attribute__((ext_vector_type(8))) short s8v;   // 8 x bf16 (4 VGPR)
typedef __attribute__((ext_vector_type(4))) float f4v;   // MFMA C/D frag

__device__ __forceinline__ unsigned short f2bf(float x) {
    union { float f; unsigned int u; } c; c.f = x;
    return (unsigned short)((c.u + 0x7fffu + ((c.u >> 16) & 1u)) >> 16);  // RTN
}
__device__ __forceinline__ unsigned int pkbf(float a, float b) {
    __hip_bfloat162 h = __float22bfloat162_rn(float2{a, b});  // x -> low 16
    union { __hip_bfloat162 v; unsigned int u; } c; c.v = h; return c.u;
}
__device__ __forceinline__ float bflo(unsigned int w) {
    union { unsigned int u; float f; } c; c.u = w << 16; return c.f;
}
__device__ __forceinline__ float bfhi(unsigned int w) {
    union { unsigned int u; float f; } c; c.u = w & 0xffff0000u; return c.f;
}

__device__ __forceinline__ void lds_load16(void* lds, const void* g) {
    __builtin_amdgcn_global_load_lds(
        (const __attribute__((address_space(1))) void*)g,
        (__attribute__((address_space(3))) void*)lds, 16, 0, 0);
}

// ---------------- Stage 0: fused conversions (unchanged R9) ----------------
__global__ __launch_bounds__(256) void conv_fused_kernel(
    const float* __restrict__ hs,
    const float* __restrict__ Wq, const float* __restrict__ Wk,
    const float* __restrict__ Wv,
    unsigned short* __restrict__ Ah, unsigned short* __restrict__ WTh)
{
    if (blockIdx.x < 2048) {
        const int idx = (blockIdx.x * 256 + threadIdx.x) * 8;
        float4 v0 = *(const float4*)&hs[idx];
        float4 v1 = *(const float4*)&hs[idx + 4];
        union { unsigned int w[4]; } pk;
        pk.w[0] = pkbf(v0.x, v0.y);
        pk.w[1] = pkbf(v0.z, v0.w);
        pk.w[2] = pkbf(v1.x, v1.y);
        pk.w[3] = pkbf(v1.z, v1.w);
        *(uint4*)&Ah[idx] = *(uint4*)&pk;
    } else {
        const int bid = blockIdx.x - 2048;
        const int z = bid >> 8;
        const int rem = bid & 255;
        const float* W = (z == 0) ? Wq : (z == 1) ? Wk : Wv;
        unsigned short* th = WTh + (size_t)z * HID * HID;

        __shared__ float tile[64][65];
        const int t = threadIdx.x;
        const int kb = (rem >> 4) * 64, nb = (rem & 15) * 64;
        const int c4 = (t & 15) * 4;
        const int r0 = t >> 4;

#pragma unroll
        for (int i = 0; i < 4; ++i) {
            int r = r0 + i * 16;
            float4 v = *(const float4*)&W[(size_t)(kb + r) * HID + nb + c4];
            tile[r][c4 + 0] = v.x; tile[r][c4 + 1] = v.y;
            tile[r][c4 + 2] = v.z; tile[r][c4 + 3] = v.w;
        }
        __syncthreads();
#pragma unroll
        for (int i = 0; i < 4; ++i) {
            int n = r0 + i * 16;
            union { unsigned int w[2]; unsigned long long q; } pk;
            pk.w[0] = pkbf(tile[c4 + 0][n], tile[c4 + 1][n]);
            pk.w[1] = pkbf(tile[c4 + 2][n], tile[c4 + 3][n]);
            *(unsigned long long*)&th[(size_t)(nb + n) * HID + kb + c4] = pk.q;
        }
    }
}

// ---------------- Stage 1: QKV projection (unchanged R9) ----------------
#define QBM 64
#define QBN 128
#define QSCALE 0.18033688011112042f   // 0.125 * log2(e)

__global__ __launch_bounds__(256, 5) void qkv_mfma_kernel(
    const unsigned short* __restrict__ Ah, const unsigned short* __restrict__ WTh,
    const float* __restrict__ bq, const float* __restrict__ bk,
    const float* __restrict__ bv,
    unsigned short* __restrict__ Qg, unsigned short* __restrict__ Khi,
    unsigned short* __restrict__ VTg)
{
    const int z = blockIdx.z;
    const float* bias = (z == 0) ? bq : (z == 1) ? bk : bv;
    const unsigned short* Bh = WTh + (size_t)z * HID * HID;

    __shared__ unsigned short AS[QBM * 64];   // 8 KB, XOR-swizzled rows
    __shared__ unsigned short BS[QBN * 64];   // 16 KB

    const int t = threadIdx.x;
    const int wave = t >> 6, lane = t & 63, quad = lane >> 4, l15 = lane & 15;
    const int sw = l15 & 7;
    const int rowBase = blockIdx.x * QBM;
    const int colBase = blockIdx.y * QBN;

    const int srow8 = lane >> 3;
    const int sc    = lane & 7;

    size_t goffA[2], goffB[4];
#pragma unroll
    for (int it = 0; it < 2; ++it) {
        const int row = (wave * 2 + it) * 8 + srow8;
        goffA[it] = (size_t)(rowBase + row) * HID + (sc ^ (row & 7)) * 8;
    }
#pragma unroll
    for (int it = 0; it < 4; ++it) {
        const int row = (wave * 4 + it) * 8 + srow8;
        goffB[it] = (size_t)(colBase + row) * HID + (sc ^ (row & 7)) * 8;
    }

    f4v acc[4][2];
#pragma unroll
    for (int mf = 0; mf < 4; ++mf)
#pragma unroll
        for (int nf = 0; nf < 2; ++nf) acc[mf][nf] = (f4v){0.f, 0.f, 0.f, 0.f};

    for (int kt = 0; kt < HID / 64; ++kt) {
        const int k0 = kt * 64;
        __syncthreads();
#pragma unroll
        for (int it = 0; it < 2; ++it)
            lds_load16(&AS[(wave * 2 + it) * 512], &Ah[goffA[it] + k0]);
#pragma unroll
        for (int it = 0; it < 4; ++it)
            lds_load16(&BS[(wave * 4 + it) * 512], &Bh[goffB[it] + k0]);
        __syncthreads();

#pragma unroll
        for (int kk = 0; kk < 2; ++kk) {
            const int csw = ((kk * 4 + quad) ^ sw) * 8;
            s8v af[4], bf[2];
#pragma unroll
            for (int mf = 0; mf < 4; ++mf)
                af[mf] = *(const s8v*)&AS[(mf * 16 + l15) * 64 + csw];
#pragma unroll
            for (int nf = 0; nf < 2; ++nf)
                bf[nf] = *(const s8v*)&BS[(wave * 32 + nf * 16 + l15) * 64 + csw];
#pragma unroll
            for (int mf = 0; mf < 4; ++mf)
#pragma unroll
                for (int nf = 0; nf < 2; ++nf)
                    acc[mf][nf] = __builtin_amdgcn_mfma_f32_16x16x32_bf16(af[mf], bf[nf], acc[mf][nf], 0, 0, 0);
        }
    }

#pragma unroll
    for (int nf = 0; nf < 2; ++nf) {
        const int n = colBase + wave * 32 + nf * 16 + l15;
        const float bb = bias[n];
        const int h = n >> 6, d = n & 63;
#pragma unroll
        for (int mf = 0; mf < 4; ++mf) {
            const int rw0 = rowBase + mf * 16 + quad * 4;
            const int b = rw0 >> 11;
            const int s0 = rw0 & (SEQ - 1);
            float c[4];
#pragma unroll
            for (int r = 0; r < 4; ++r) c[r] = acc[mf][nf][r] + bb;
            if (z == 0) {
#pragma unroll
                for (int r = 0; r < 4; ++r)
                    Qg[((size_t)(b * NHEADS + h) * SEQ + s0 + r) * HDIM + d] = f2bf(c[r] * QSCALE);
            } else if (z == 1) {
#pragma unroll
                for (int r = 0; r < 4; ++r)
                    Khi[((size_t)(b * NHEADS + h) * SEQ + s0 + r) * HDIM + d] = f2bf(c[r]);
            } else {
                union { unsigned int w[2]; unsigned long long q; } pk;
                pk.w[0] = pkbf(c[0], c[1]);
                pk.w[1] = pkbf(c[2], c[3]);
                *(unsigned long long*)&VTg[((size_t)(b * NHEADS + h) * HDIM + d) * SEQ + s0] = pk.q;
            }
        }
    }
}

// ---------------- Stage 2: MFMA flash attention v7 -------------------------
// BARRIER-FREE K-loop: K [s][d] and V^T [d][s] fragments load DIRECTLY from
// global (L1/L2-resident: 16 same-bh blocks per XCD share tiles) into a
// 2-tile register pipeline. LDS keeps only the wave-private P round-trip.
#define BC 64

struct Frags { s8v k[8]; s8v v[8]; };

__device__ __forceinline__ void load_tile(
    const unsigned short* __restrict__ kb, const unsigned short* __restrict__ vb,
    int kt, int l15, int quad, Frags& f)
{
#pragma unroll
    for (int mf = 0; mf < 4; ++mf)
#pragma unroll
        for (int ds = 0; ds < 2; ++ds)
            f.k[mf * 2 + ds] = *(const s8v*)&kb[(size_t)(kt * BC + mf * 16 + l15) * HDIM + ds * 32 + quad * 8];
#pragma unroll
    for (int ks = 0; ks < 2; ++ks)
#pragma unroll
        for (int nf = 0; nf < 4; ++nf)
            f.v[ks * 4 + nf] = *(const s8v*)&vb[(size_t)(nf * 16 + l15) * SEQ + kt * BC + ks * 32 + quad * 8];
}

__device__ __forceinline__ void attn_step(
    const Frags& f, const float* __restrict__ mrow, int kt,
    const s8v (&qh)[2][2], f4v (&oacc)[2][4], float (&l_r)[2],
    unsigned short* __restrict__ pw, int quad, int l15, int sw)
{
    float4 msv[4];
#pragma unroll
    for (int mf = 0; mf < 4; ++mf)
        msv[mf] = *(const float4*)&mrow[kt * BC + mf * 16 + quad * 4];

    // ---- S^T = K.Q^T : A = K frags (regs), B = Q regs ----
    f4v sacc[2][4];
#pragma unroll
    for (int qf = 0; qf < 2; ++qf)
#pragma unroll
        for (int mf = 0; mf < 4; ++mf) sacc[qf][mf] = (f4v){0.f, 0.f, 0.f, 0.f};
#pragma unroll
    for (int mf = 0; mf < 4; ++mf)
#pragma unroll
        for (int ds = 0; ds < 2; ++ds)
#pragma unroll
            for (int qf = 0; qf < 2; ++qf)
                sacc[qf][mf] = __builtin_amdgcn_mfma_f32_16x16x32_bf16(f.k[mf * 2 + ds], qh[qf][ds], sacc[qf][mf], 0, 0, 0);

    // ---- p = exp2(s) * mask; pack; l from ROUNDED p; P -> wave-private LDS ----
#pragma unroll
    for (int qf = 0; qf < 2; ++qf) {
        float psum = 0.f;
        const int prow = (qf * 16 + l15) * BC;
#pragma unroll
        for (int mf = 0; mf < 4; ++mf) {
            const float* mp = (const float*)&msv[mf];
            float p0 = __builtin_amdgcn_exp2f(sacc[qf][mf][0]) * mp[0];
            float p1 = __builtin_amdgcn_exp2f(sacc[qf][mf][1]) * mp[1];
            float p2 = __builtin_amdgcn_exp2f(sacc[qf][mf][2]) * mp[2];
            float p3 = __builtin_amdgcn_exp2f(sacc[qf][mf][3]) * mp[3];
            union { unsigned int w[2]; unsigned long long q; } pk;
            pk.w[0] = pkbf(p0, p1);
            pk.w[1] = pkbf(p2, p3);
            psum += bflo(pk.w[0]) + bfhi(pk.w[0]) + bflo(pk.w[1]) + bfhi(pk.w[1]);
            const int c16 = (mf * 2 + (quad >> 1)) ^ sw;
            *(unsigned long long*)&pw[prow + c16 * 8 + (quad & 1) * 4] = pk.q;
        }
        l_r[qf] += psum;
    }

    // ---- PV: A = P frags (LDS), B = V^T frags (regs) ----
#pragma unroll
    for (int ks = 0; ks < 2; ++ks) {
        const int csw = ((ks * 4 + quad) ^ sw) * 8;
        s8v pa0 = *(const s8v*)&pw[(0 * 16 + l15) * BC + csw];
        s8v pa1 = *(const s8v*)&pw[(1 * 16 + l15) * BC + csw];
#pragma unroll
        for (int nf = 0; nf < 4; ++nf) {
            oacc[0][nf] = __builtin_amdgcn_mfma_f32_16x16x32_bf16(pa0, f.v[ks * 4 + nf], oacc[0][nf], 0, 0, 0);
            oacc[1][nf] = __builtin_amdgcn_mfma_f32_16x16x32_bf16(pa1, f.v[ks * 4 + nf], oacc[1][nf], 0, 0, 0);
        }
    }
}

__global__ __launch_bounds__(256, 2) void attn_mfma_kernel(
    const unsigned short* __restrict__ Qg, const unsigned short* __restrict__ Khi,
    const unsigned short* __restrict__ VTg,
    const float* __restrict__ mask, float* __restrict__ out)
{
    __shared__ unsigned short Pbuf[4][32 * BC];    // 16 KB, per-wave, swizzled

    const int t = threadIdx.x;
    const int wave = t >> 6, lane = t & 63, quad = lane >> 4, l15 = lane & 15;
    const int sw = l15 & 7;
    const int bh = blockIdx.x, b = bh >> 4, h = bh & (NHEADS - 1);
    const int qbase = blockIdx.y * 128 + wave * 32;

    const size_t hb = (size_t)bh * SEQ * HDIM;
    const unsigned short* kbase = Khi + hb;
    const unsigned short* vbase = VTg + hb;
    const float* mrow = mask + b * SEQ;
    unsigned short* pw = &Pbuf[wave][0];

    // Q B-frags in registers: lane n=l15 -> q, k = ds*32+quad*8+j.
    s8v qh[2][2];
#pragma unroll
    for (int qf = 0; qf < 2; ++qf)
#pragma unroll
        for (int ds = 0; ds < 2; ++ds) {
            size_t off = hb + (size_t)(qbase + qf * 16 + l15) * HDIM + ds * 32 + quad * 8;
            qh[qf][ds] = *(const s8v*)&Qg[off];
        }

    f4v oacc[2][4];
#pragma unroll
    for (int qf = 0; qf < 2; ++qf)
#pragma unroll
        for (int nf = 0; nf < 4; ++nf) oacc[qf][nf] = (f4v){0.f, 0.f, 0.f, 0.f};
    float l_r[2] = {0.f, 0.f};

    Frags fA, fB;
    load_tile(kbase, vbase, 0, l15, quad, fA);

    for (int kt = 0; kt < SEQ / BC; kt += 2) {
        load_tile(kbase, vbase, kt + 1, l15, quad, fB);      // prefetch (full step ahead)
        attn_step(fA, mrow, kt, qh, oacc, l_r, pw, quad, l15, sw);
        if (kt + 2 < SEQ / BC)
            load_tile(kbase, vbase, kt + 2, l15, quad, fA);  // prefetch
        attn_step(fB, mrow, kt + 1, qh, oacc, l_r, pw, quad, l15, sw);
    }

    // ---- epilogue: quad-reduce l, normalize, write [b][s][h*64+d] ----
#pragma unroll
    for (int qf = 0; qf < 2; ++qf) {
        float v = l_r[qf];
        v += __shfl_xor(v, 16);
        v += __shfl_xor(v, 32);
        float lv[4];
#pragma unroll
        for (int r = 0; r < 4; ++r)
            lv[r] = 1.0f / __shfl(v, quad * 4 + r);
#pragma unroll
        for (int nf = 0; nf < 4; ++nf)
#pragma unroll
            for (int r = 0; r < 4; ++r) {
                int q = qbase + qf * 16 + quad * 4 + r;
                int d = nf * 16 + l15;
                out[((size_t)b * SEQ + q) * HID + h * HDIM + d] = oacc[qf][nf][r] * lv[r];
            }
    }
}

extern "C" void kernel_launch(void* const* d_in, const int* in_sizes, int n_in,
                              void* d_out, int out_size, void* d_ws, size_t ws_size,
                              hipStream_t stream) {
    const float* hs   = (const float*)d_in[0];
    const float* mask = (const float*)d_in[1];
    const float* Wq   = (const float*)d_in[2];
    const float* bq   = (const float*)d_in[3];
    const float* Wk   = (const float*)d_in[4];
    const float* bk   = (const float*)d_in[5];
    const float* Wv   = (const float*)d_in[6];
    const float* bv   = (const float*)d_in[7];
    float* out = (float*)d_out;

    const size_t N = (size_t)MROWS * HID;        // 4.19M u16 per array
    unsigned short* Qg  = (unsigned short*)d_ws;
    unsigned short* Khi = Qg + N;
    unsigned short* VTg = Qg + 2 * N;
    unsigned short* Ah  = Qg + 3 * N;
    unsigned short* WTh = Qg + 4 * N;            // 3*HID*HID u16

    conv_fused_kernel<<<2048 + 768, 256, 0, stream>>>(hs, Wq, Wk, Wv, Ah, WTh);

    dim3 g1(MROWS / QBM, HID / QBN, 3);   // 64 x 8 x 3 = 1536 blocks (6/CU)
    qkv_mfma_kernel<<<g1, 256, 0, stream>>>(Ah, WTh, bq, bk, bv, Qg, Khi, VTg);

    dim3 g2(BHT, SEQ / 128);              // 32 x 16 (bh-major: K/V stay in one XCD's L2)
    attn_mfma_kernel<<<g2, 256, 0, stream>>>(Qg, Khi, VTg, mask, out);
}

// Round 12
// 174.644 us; speedup vs baseline: 1.4773x; 1.4773x over previous
//
#include <hip/hip_runtime.h>
#include <hip/hip_bf16.h>
#include <cstddef>
#include <cstdint>

#define HID 1024
#define NHEADS 16
#define HDIM 64
#define BATCH 2
#define SEQ 2048
#define MROWS (BATCH * SEQ)   // 4096
#define BHT (BATCH * NHEADS)  // 32

typedef __attribute__((ext_vector_type(8))) short s8v;   // 8 x bf16 (4 VGPR)
typedef __attribute__((ext_vector_type(4))) float f4v;   // MFMA C/D frag

__device__ __forceinline__ unsigned short f2bf(float x) {
    union { float f; unsigned int u; } c; c.f = x;
    return (unsigned short)((c.u + 0x7fffu + ((c.u >> 16) & 1u)) >> 16);  // RTN
}
__device__ __forceinline__ unsigned int pkbf(float a, float b) {
    __hip_bfloat162 h = __float22bfloat162_rn(float2{a, b});  // x -> low 16
    union { __hip_bfloat162 v; unsigned int u; } c; c.v = h; return c.u;
}
__device__ __forceinline__ float bflo(unsigned int w) {
    union { unsigned int u; float f; } c; c.u = w << 16; return c.f;
}
__device__ __forceinline__ float bfhi(unsigned int w) {
    union { unsigned int u; float f; } c; c.u = w & 0xffff0000u; return c.f;
}

__device__ __forceinline__ void lds_load16(void* lds, const void* g) {
    __builtin_amdgcn_global_load_lds(
        (const __attribute__((address_space(1))) void*)g,
        (__attribute__((address_space(3))) void*)lds, 16, 0, 0);
}

// ---------------- Stage 0: fused conversions (unchanged R9) ----------------
__global__ __launch_bounds__(256) void conv_fused_kernel(
    const float* __restrict__ hs,
    const float* __restrict__ Wq, const float* __restrict__ Wk,
    const float* __restrict__ Wv,
    unsigned short* __restrict__ Ah, unsigned short* __restrict__ WTh)
{
    if (blockIdx.x < 2048) {
        const int idx = (blockIdx.x * 256 + threadIdx.x) * 8;
        float4 v0 = *(const float4*)&hs[idx];
        float4 v1 = *(const float4*)&hs[idx + 4];
        union { unsigned int w[4]; } pk;
        pk.w[0] = pkbf(v0.x, v0.y);
        pk.w[1] = pkbf(v0.z, v0.w);
        pk.w[2] = pkbf(v1.x, v1.y);
        pk.w[3] = pkbf(v1.z, v1.w);
        *(uint4*)&Ah[idx] = *(uint4*)&pk;
    } else {
        const int bid = blockIdx.x - 2048;
        const int z = bid >> 8;
        const int rem = bid & 255;
        const float* W = (z == 0) ? Wq : (z == 1) ? Wk : Wv;
        unsigned short* th = WTh + (size_t)z * HID * HID;

        __shared__ float tile[64][65];
        const int t = threadIdx.x;
        const int kb = (rem >> 4) * 64, nb = (rem & 15) * 64;
        const int c4 = (t & 15) * 4;
        const int r0 = t >> 4;

#pragma unroll
        for (int i = 0; i < 4; ++i) {
            int r = r0 + i * 16;
            float4 v = *(const float4*)&W[(size_t)(kb + r) * HID + nb + c4];
            tile[r][c4 + 0] = v.x; tile[r][c4 + 1] = v.y;
            tile[r][c4 + 2] = v.z; tile[r][c4 + 3] = v.w;
        }
        __syncthreads();
#pragma unroll
        for (int i = 0; i < 4; ++i) {
            int n = r0 + i * 16;
            union { unsigned int w[2]; unsigned long long q; } pk;
            pk.w[0] = pkbf(tile[c4 + 0][n], tile[c4 + 1][n]);
            pk.w[1] = pkbf(tile[c4 + 2][n], tile[c4 + 3][n]);
            *(unsigned long long*)&th[(size_t)(nb + n) * HID + kb + c4] = pk.q;
        }
    }
}

// ---------------- Stage 1: QKV projection v2 --------------------------------
// z2=0: Q+K PAIRED block (share the A tile): 128x128, 4 waves of 64x64, BK=64.
//   Per kk: 12 b128 reads feed 32 MFMA (ratio 0.375). Swapped operands so the
//   epilogue packs 4 consecutive d -> b64 stores into [bh][s][d].
// z2=1: V block: 128x128, wave 64x64, natural orientation, b64 into VT [bh][d][s].
#define QSCALE 0.18033688011112042f   // 0.125 * log2(e)

__global__ __launch_bounds__(256, 2) void qkv_mfma_kernel(
    const unsigned short* __restrict__ Ah, const unsigned short* __restrict__ WTh,
    const float* __restrict__ bq, const float* __restrict__ bk,
    const float* __restrict__ bv,
    unsigned short* __restrict__ Qg, unsigned short* __restrict__ Khi,
    unsigned short* __restrict__ VTg)
{
    __shared__ unsigned short S[24576];   // 48 KB
    unsigned short* AS = S;               // 128 x 64 (16 KB)
    unsigned short* B0 = S + 8192;        // 128 x 64
    unsigned short* B1 = S + 16384;       // 128 x 64 (QK path only)

    const int z2 = blockIdx.z;
    const int t = threadIdx.x;
    const int wave = t >> 6, lane = t & 63, quad = lane >> 4, l15 = lane & 15;
    const int sw = l15 & 7;
    const int wm = wave >> 1, wn = wave & 1;
    const int rowBase = blockIdx.x * 128;
    const int colBase = blockIdx.y * 128;

    const int srow8 = lane >> 3;
    const int sc    = lane & 7;

    const unsigned short* BhQ = WTh;                           // Wq^T
    const unsigned short* BhK = WTh + (size_t)HID * HID;       // Wk^T
    const unsigned short* BhV = WTh + (size_t)2 * HID * HID;   // Wv^T

    // lane-invariant staging offsets: 16 slices per 128x64 tile, 4 per wave
    size_t goffA[4], goffB[4];
#pragma unroll
    for (int it = 0; it < 4; ++it) {
        const int row = (wave * 4 + it) * 8 + srow8;
        const int gx = (sc ^ (row & 7)) * 8;
        goffA[it] = (size_t)(rowBase + row) * HID + gx;
        goffB[it] = (size_t)(colBase + row) * HID + gx;
    }

    if (z2 == 0) {
        // ---------------- Q + K paired ----------------
        f4v accq[4][4], acck[4][4];
#pragma unroll
        for (int mf = 0; mf < 4; ++mf)
#pragma unroll
            for (int nf = 0; nf < 4; ++nf) {
                accq[mf][nf] = (f4v){0.f, 0.f, 0.f, 0.f};
                acck[mf][nf] = (f4v){0.f, 0.f, 0.f, 0.f};
            }

        for (int kt = 0; kt < HID / 64; ++kt) {
            const int k0 = kt * 64;
            __syncthreads();
#pragma unroll
            for (int it = 0; it < 4; ++it) {
                lds_load16(&AS[(wave * 4 + it) * 512], &Ah[goffA[it] + k0]);
                lds_load16(&B0[(wave * 4 + it) * 512], &BhQ[goffB[it] + k0]);
                lds_load16(&B1[(wave * 4 + it) * 512], &BhK[goffB[it] + k0]);
            }
            __syncthreads();

#pragma unroll
            for (int kk = 0; kk < 2; ++kk) {
                const int csw = ((kk * 4 + quad) ^ sw) * 8;
                s8v af[4], bfq[4], bfk[4];
#pragma unroll
                for (int mf = 0; mf < 4; ++mf)
                    af[mf] = *(const s8v*)&AS[(wm * 64 + mf * 16 + l15) * 64 + csw];
#pragma unroll
                for (int nf = 0; nf < 4; ++nf) {
                    bfq[nf] = *(const s8v*)&B0[(wn * 64 + nf * 16 + l15) * 64 + csw];
                    bfk[nf] = *(const s8v*)&B1[(wn * 64 + nf * 16 + l15) * 64 + csw];
                }
                // swapped operands: C[n][m] -> lane's 4 values = 4 consecutive d
#pragma unroll
                for (int mf = 0; mf < 4; ++mf)
#pragma unroll
                    for (int nf = 0; nf < 4; ++nf) {
                        accq[mf][nf] = __builtin_amdgcn_mfma_f32_16x16x32_bf16(bfq[nf], af[mf], accq[mf][nf], 0, 0, 0);
                        acck[mf][nf] = __builtin_amdgcn_mfma_f32_16x16x32_bf16(bfk[nf], af[mf], acck[mf][nf], 0, 0, 0);
                    }
            }
        }

        // epilogue: acc[mf][nf][r] = C[s = rowBase+wm*64+mf*16+l15][n = colBase+wn*64+nf*16+quad*4+r]
#pragma unroll
        for (int nf = 0; nf < 4; ++nf) {
            const int n0 = colBase + wn * 64 + nf * 16 + quad * 4;
            const float4 bbq = *(const float4*)&bq[n0];
            const float4 bbk = *(const float4*)&bk[n0];
            const int h = n0 >> 6, d0 = n0 & 63;
#pragma unroll
            for (int mf = 0; mf < 4; ++mf) {
                const int rw = rowBase + wm * 64 + mf * 16 + l15;
                const int b = rw >> 11;
                const int ss = rw & (SEQ - 1);
                const size_t base = ((size_t)(b * NHEADS + h) * SEQ + ss) * HDIM + d0;
                union { unsigned int w[2]; unsigned long long q; } pk;
                pk.w[0] = pkbf((accq[mf][nf][0] + bbq.x) * QSCALE, (accq[mf][nf][1] + bbq.y) * QSCALE);
                pk.w[1] = pkbf((accq[mf][nf][2] + bbq.z) * QSCALE, (accq[mf][nf][3] + bbq.w) * QSCALE);
                *(unsigned long long*)&Qg[base] = pk.q;
                pk.w[0] = pkbf(acck[mf][nf][0] + bbk.x, acck[mf][nf][1] + bbk.y);
                pk.w[1] = pkbf(acck[mf][nf][2] + bbk.z, acck[mf][nf][3] + bbk.w);
                *(unsigned long long*)&Khi[base] = pk.q;
            }
        }
    } else {
        // ---------------- V ----------------
        f4v acc[4][4];
#pragma unroll
        for (int mf = 0; mf < 4; ++mf)
#pragma unroll
            for (int nf = 0; nf < 4; ++nf) acc[mf][nf] = (f4v){0.f, 0.f, 0.f, 0.f};

        for (int kt = 0; kt < HID / 64; ++kt) {
            const int k0 = kt * 64;
            __syncthreads();
#pragma unroll
            for (int it = 0; it < 4; ++it) {
                lds_load16(&AS[(wave * 4 + it) * 512], &Ah[goffA[it] + k0]);
                lds_load16(&B0[(wave * 4 + it) * 512], &BhV[goffB[it] + k0]);
            }
            __syncthreads();

#pragma unroll
            for (int kk = 0; kk < 2; ++kk) {
                const int csw = ((kk * 4 + quad) ^ sw) * 8;
                s8v af[4], bf[4];
#pragma unroll
                for (int mf = 0; mf < 4; ++mf)
                    af[mf] = *(const s8v*)&AS[(wm * 64 + mf * 16 + l15) * 64 + csw];
#pragma unroll
                for (int nf = 0; nf < 4; ++nf)
                    bf[nf] = *(const s8v*)&B0[(wn * 64 + nf * 16 + l15) * 64 + csw];
#pragma unroll
                for (int mf = 0; mf < 4; ++mf)
#pragma unroll
                    for (int nf = 0; nf < 4; ++nf)
                        acc[mf][nf] = __builtin_amdgcn_mfma_f32_16x16x32_bf16(af[mf], bf[nf], acc[mf][nf], 0, 0, 0);
            }
        }

        // epilogue: acc[mf][nf][r] = C[s = rowBase+wm*64+mf*16+quad*4+r][n = colBase+wn*64+nf*16+l15]
#pragma unroll
        for (int nf = 0; nf < 4; ++nf) {
            const int n = colBase + wn * 64 + nf * 16 + l15;
            const float bb = bv[n];
            const int h = n >> 6, d = n & 63;
#pragma unroll
            for (int mf = 0; mf < 4; ++mf) {
                const int rw0 = rowBase + wm * 64 + mf * 16 + quad * 4;
                const int b = rw0 >> 11;
                const int s0 = rw0 & (SEQ - 1);
                union { unsigned int w[2]; unsigned long long q; } pk;
                pk.w[0] = pkbf(acc[mf][nf][0] + bb, acc[mf][nf][1] + bb);
                pk.w[1] = pkbf(acc[mf][nf][2] + bb, acc[mf][nf][3] + bb);
                *(unsigned long long*)&VTg[((size_t)(b * NHEADS + h) * HDIM + d) * SEQ + s0] = pk.q;
            }
        }
    }
}

// ---------------- Stage 2: MFMA flash attention (R9 63us version) ----------
#define BC 64

__global__ __launch_bounds__(256, 2) void attn_mfma_kernel(
    const unsigned short* __restrict__ Qg, const unsigned short* __restrict__ Khi,
    const unsigned short* __restrict__ VTg,
    const float* __restrict__ mask, float* __restrict__ out)
{
    __shared__ unsigned short Kb[2][BC * HDIM];    // 2 x 8 KB, swizzled
    __shared__ unsigned short Vb[2][BC * HDIM];    // 2 x 8 KB, swizzled (V^T)
    __shared__ unsigned short Pbuf[4][32 * BC];    // 16 KB, per-wave, swizzled

    const int t = threadIdx.x;
    const int wave = t >> 6, lane = t & 63, quad = lane >> 4, l15 = lane & 15;
    const int sw = l15 & 7;
    const int bh = blockIdx.x, b = bh >> 4, h = bh & (NHEADS - 1);
    const int qbase = blockIdx.y * 128 + wave * 32;

    const size_t hb = (size_t)bh * SEQ * HDIM;
    const unsigned short* kbase = Khi + hb;
    const unsigned short* vbase = VTg + hb;
    const float* mrow = mask + b * SEQ;

    s8v qh[2][2];
#pragma unroll
    for (int qf = 0; qf < 2; ++qf)
#pragma unroll
        for (int ds = 0; ds < 2; ++ds) {
            size_t off = hb + (size_t)(qbase + qf * 16 + l15) * HDIM + ds * 32 + quad * 8;
            qh[qf][ds] = *(const s8v*)&Qg[off];
        }

    f4v oacc[2][4];
#pragma unroll
    for (int qf = 0; qf < 2; ++qf)
#pragma unroll
        for (int nf = 0; nf < 4; ++nf) oacc[qf][nf] = (f4v){0.f, 0.f, 0.f, 0.f};
    float l_r[2] = {0.f, 0.f};

    const int srow8 = lane >> 3;
    const int sc    = lane & 7;
    int koff[2], voff[2];
#pragma unroll
    for (int it = 0; it < 2; ++it) {
        const int row = (wave * 2 + it) * 8 + srow8;
        const int gx = (sc ^ (row & 7)) * 8;
        koff[it] = row * HDIM + gx;
        voff[it] = row * SEQ + gx;
    }

#pragma unroll
    for (int it = 0; it < 2; ++it) {
        const int i = wave * 2 + it;
        lds_load16(&Kb[0][i * 512], kbase + koff[it]);
        lds_load16(&Vb[0][i * 512], vbase + voff[it]);
    }
    __syncthreads();

    for (int kt = 0; kt < SEQ / BC; ++kt) {
        const int cur = kt & 1;
        if (kt + 1 < SEQ / BC) {
            const int nxt = cur ^ 1;
#pragma unroll
            for (int it = 0; it < 2; ++it) {
                const int i = wave * 2 + it;
                lds_load16(&Kb[nxt][i * 512], kbase + (kt + 1) * BC * HDIM + koff[it]);
                lds_load16(&Vb[nxt][i * 512], vbase + (kt + 1) * BC + voff[it]);
            }
        }
        float4 msv[4];
#pragma unroll
        for (int mf = 0; mf < 4; ++mf)
            msv[mf] = *(const float4*)&mrow[kt * BC + mf * 16 + quad * 4];

        f4v sacc[2][4];
#pragma unroll
        for (int qf = 0; qf < 2; ++qf)
#pragma unroll
            for (int mf = 0; mf < 4; ++mf) sacc[qf][mf] = (f4v){0.f, 0.f, 0.f, 0.f};
#pragma unroll
        for (int mf = 0; mf < 4; ++mf) {
#pragma unroll
            for (int ds = 0; ds < 2; ++ds) {
                s8v kh = *(const s8v*)&Kb[cur][(mf * 16 + l15) * HDIM + (((ds * 4 + quad) ^ sw) * 8)];
#pragma unroll
                for (int qf = 0; qf < 2; ++qf)
                    sacc[qf][mf] = __builtin_amdgcn_mfma_f32_16x16x32_bf16(kh, qh[qf][ds], sacc[qf][mf], 0, 0, 0);
            }
        }

#pragma unroll
        for (int qf = 0; qf < 2; ++qf) {
            float psum = 0.f;
            const int prow = (qf * 16 + l15) * BC;
#pragma unroll
            for (int mf = 0; mf < 4; ++mf) {
                const float* mp = (const float*)&msv[mf];
                float p0 = __builtin_amdgcn_exp2f(sacc[qf][mf][0]) * mp[0];
                float p1 = __builtin_amdgcn_exp2f(sacc[qf][mf][1]) * mp[1];
                float p2 = __builtin_amdgcn_exp2f(sacc[qf][mf][2]) * mp[2];
                float p3 = __builtin_amdgcn_exp2f(sacc[qf][mf][3]) * mp[3];
                union { unsigned int w[2]; unsigned long long q; } pk;
                pk.w[0] = pkbf(p0, p1);
                pk.w[1] = pkbf(p2, p3);
                psum += bflo(pk.w[0]) + bfhi(pk.w[0]) + bflo(pk.w[1]) + bfhi(pk.w[1]);
                const int c16 = (mf * 2 + (quad >> 1)) ^ sw;
                *(unsigned long long*)&Pbuf[wave][prow + c16 * 8 + (quad & 1) * 4] = pk.q;
            }
            l_r[qf] += psum;
        }

#pragma unroll
        for (int ks = 0; ks < 2; ++ks) {
            const int csw = ((ks * 4 + quad) ^ sw) * 8;
            s8v pa0 = *(const s8v*)&Pbuf[wave][(0 * 16 + l15) * BC + csw];
            s8v pa1 = *(const s8v*)&Pbuf[wave][(1 * 16 + l15) * BC + csw];
#pragma unroll
            for (int nf = 0; nf < 4; ++nf) {
                s8v vb = *(const s8v*)&Vb[cur][(nf * 16 + l15) * BC + csw];
                oacc[0][nf] = __builtin_amdgcn_mfma_f32_16x16x32_bf16(pa0, vb, oacc[0][nf], 0, 0, 0);
                oacc[1][nf] = __builtin_amdgcn_mfma_f32_16x16x32_bf16(pa1, vb, oacc[1][nf], 0, 0, 0);
            }
        }
        __syncthreads();
    }

#pragma unroll
    for (int qf = 0; qf < 2; ++qf) {
        float v = l_r[qf];
        v += __shfl_xor(v, 16);
        v += __shfl_xor(v, 32);
        float lv[4];
#pragma unroll
        for (int r = 0; r < 4; ++r)
            lv[r] = 1.0f / __shfl(v, quad * 4 + r);
#pragma unroll
        for (int nf = 0; nf < 4; ++nf)
#pragma unroll
            for (int r = 0; r < 4; ++r) {
                int q = qbase + qf * 16 + quad * 4 + r;
                int d = nf * 16 + l15;
                out[((size_t)b * SEQ + q) * HID + h * HDIM + d] = oacc[qf][nf][r] * lv[r];
            }
    }
}

extern "C" void kernel_launch(void* const* d_in, const int* in_sizes, int n_in,
                              void* d_out, int out_size, void* d_ws, size_t ws_size,
                              hipStream_t stream) {
    const float* hs   = (const float*)d_in[0];
    const float* mask = (const float*)d_in[1];
    const float* Wq   = (const float*)d_in[2];
    const float* bq   = (const float*)d_in[3];
    const float* Wk   = (const float*)d_in[4];
    const float* bk   = (const float*)d_in[5];
    const float* Wv   = (const float*)d_in[6];
    const float* bv   = (const float*)d_in[7];
    float* out = (float*)d_out;

    const size_t N = (size_t)MROWS * HID;        // 4.19M u16 per array
    unsigned short* Qg  = (unsigned short*)d_ws;
    unsigned short* Khi = Qg + N;
    unsigned short* VTg = Qg + 2 * N;
    unsigned short* Ah  = Qg + 3 * N;
    unsigned short* WTh = Qg + 4 * N;            // 3*HID*HID u16

    conv_fused_kernel<<<2048 + 768, 256, 0, stream>>>(hs, Wq, Wk, Wv, Ah, WTh);

    dim3 g1(MROWS / 128, HID / 128, 2);   // 32 x 8 x 2 = 512 blocks (2/CU)
    qkv_mfma_kernel<<<g1, 256, 0, stream>>>(Ah, WTh, bq, bk, bv, Qg, Khi, VTg);

    dim3 g2(BHT, SEQ / 128);              // 32 x 16 (bh-major: K/V stay in one XCD's L2)
    attn_mfma_kernel<<<g2, 256, 0, stream>>>(Qg, Khi, VTg, mask, out);
}